// Round 1
// baseline (1552.518 us; speedup 1.0000x reference)
//
#include <hip/hip_runtime.h>

#define BATCH 64
#define SEQT  2048
#define DIM   256   // INPUT_SIZE
#define HID   256   // HIDDEN_SIZE

typedef _Float16 half_t;
typedef _Float16 half2_t __attribute__((ext_vector_type(2)));
typedef _Float16 half8_t __attribute__((ext_vector_type(8)));
typedef float    float4_t __attribute__((ext_vector_type(4)));

__device__ __forceinline__ half2_t mkh2(float a, float b) {
  half2_t r; r[0] = (half_t)a; r[1] = (half_t)b; return r;
}

__device__ __forceinline__ half8_t cvt8(float4_t a, float4_t b) {
  half8_t r;
  r[0] = (half_t)a[0]; r[1] = (half_t)a[1]; r[2] = (half_t)a[2]; r[3] = (half_t)a[3];
  r[4] = (half_t)b[0]; r[5] = (half_t)b[1]; r[6] = (half_t)b[2]; r[7] = (half_t)b[3];
  return r;
}

// ---------------------------------------------------------------------------
// Kernel 1: xproj  P[m,n] = sum_k x[m,k] * Wxh[n,k] + bh[n]   (M = BATCH*SEQT)
// P is written into d_out (fp32); the recurrence kernel consumes and then
// overwrites each [b,t,:] slot in order.
// 256 threads = 4 waves; each wave computes a 16(M) x 256(N) tile via
// mfma_f32_16x16x32_f16, fragments loaded straight from global (fp32->f16).
// A-frag: lane l holds A[l&15][8*(l>>4)+e]; B[k][n] = Wxh[n][k] so B-frag is
// a contiguous 32B fp32 read of the Wxh row.  C/D: col=l&15, row=(l>>4)*4+r.
// ---------------------------------------------------------------------------
__global__ __launch_bounds__(256) void xproj_kernel(
    const float* __restrict__ x, const float* __restrict__ Wxh,
    const float* __restrict__ bh, float* __restrict__ out)
{
  const int lane = threadIdx.x & 63;
  const int wave = threadIdx.x >> 6;
  const int r16  = lane & 15;   // A row / B col / C col within tile
  const int kg   = lane >> 4;   // 0..3
  const long m0  = (long)blockIdx.x * 64 + wave * 16;

  // A fragments for the full K=256 (8 frags), held in registers
  half8_t a[8];
  const float* xr = x + (m0 + r16) * (long)DIM + kg * 8;
  #pragma unroll
  for (int kf = 0; kf < 8; ++kf) {
    float4_t x0 = *(const float4_t*)(xr + kf * 32);
    float4_t x1 = *(const float4_t*)(xr + kf * 32 + 4);
    a[kf] = cvt8(x0, x1);
  }

  for (int nt = 0; nt < 16; ++nt) {
    const float* wr = Wxh + (nt * 16 + r16) * (long)DIM + kg * 8;
    float bb = bh[nt * 16 + r16];
    float4_t acc = {bb, bb, bb, bb};
    #pragma unroll
    for (int kf = 0; kf < 8; ++kf) {
      float4_t w0 = *(const float4_t*)(wr + kf * 32);
      float4_t w1 = *(const float4_t*)(wr + kf * 32 + 4);
      half8_t bfrag = cvt8(w0, w1);
      acc = __builtin_amdgcn_mfma_f32_16x16x32_f16(a[kf], bfrag, acc, 0, 0, 0);
    }
    float* op = out + (m0 + kg * 4) * (long)HID + nt * 16 + r16;
    #pragma unroll
    for (int r = 0; r < 4; ++r) op[(long)r * HID] = acc[r];
  }
}

// ---------------------------------------------------------------------------
// Kernel 2: recurrence  h_t = relu(xp_t + W_hh h_{t-1}), one block per batch.
// 256 threads: thread (jq = tid>>2, g = tid&3) computes 4 outputs
// j in {4jq..4jq+3} over K-chunk [64g, 64g+64) -> 128 v_dot2_f32_f16/thread.
// Weights live in VGPRs (f16, slot-rotated so LDS reads are conflict-free and
// weight indexing stays compile-time).  Partials reduced with 2x shfl_xor
// (lanes l^1, l^2 share jq).  h double-buffered in LDS as f16; xp prefetched
// one step ahead from d_out; ONE barrier per step.
// ---------------------------------------------------------------------------
__global__ __launch_bounds__(256, 1) void rnn_kernel(
    const float* __restrict__ Whh, float* __restrict__ out, int T)
{
  __shared__ alignas(16) half_t hbuf[2][HID];
  const int tid = threadIdx.x;
  const int g   = tid & 3;
  const int jq  = tid >> 2;
  const int j0  = jq * 4;
  const int c0  = g * 64;
  const long base = (long)blockIdx.x * SEQT * HID;

  // Load per-thread weights (fp32 -> f16), pre-rotated by the same slot
  // permutation the LDS h-reads use, so the hot loop indexes w[] statically.
  half2_t w[4][32];
  #pragma unroll
  for (int i = 0; i < 4; ++i) {
    const float* wr = Whh + (long)(j0 + i) * HID + c0;
    #pragma unroll
    for (int s = 0; s < 8; ++s) {
      const int slot = (s + 2 * g) & 7;
      float4_t v0 = *(const float4_t*)(wr + slot * 8);
      float4_t v1 = *(const float4_t*)(wr + slot * 8 + 4);
      w[i][s * 4 + 0] = mkh2(v0[0], v0[1]);
      w[i][s * 4 + 1] = mkh2(v0[2], v0[3]);
      w[i][s * 4 + 2] = mkh2(v1[0], v1[1]);
      w[i][s * 4 + 3] = mkh2(v1[2], v1[3]);
    }
  }

  // h_0 = 0
  if (tid < 128) ((half2_t*)hbuf[0])[tid] = mkh2(0.f, 0.f);

  float4_t xp_cur = {0.f, 0.f, 0.f, 0.f};
  if (g == 0) xp_cur = *(const float4_t*)(out + base + j0);
  __syncthreads();

  #pragma unroll 1
  for (int t = 0; t < T; ++t) {
    const int cur = t & 1;

    // prefetch next step's xp (hides HBM latency under the dot2 work)
    float4_t xp_nxt = xp_cur;
    if (g == 0 && t + 1 < T)
      xp_nxt = *(const float4_t*)(out + base + (long)(t + 1) * HID + j0);

    float acc0 = 0.f, acc1 = 0.f, acc2 = 0.f, acc3 = 0.f;
    const half_t* hc = hbuf[cur] + c0;
    #pragma unroll
    for (int s = 0; s < 8; ++s) {
      const int slot = (s + 2 * g) & 7;   // 4 g-groups hit 4 distinct banks
      half8_t hv = *(const half8_t*)(hc + slot * 8);
      #pragma unroll
      for (int c = 0; c < 4; ++c) {
        half2_t p; p[0] = hv[2 * c]; p[1] = hv[2 * c + 1];
        const int k = s * 4 + c;    // compile-time index into w[]
        acc0 = __builtin_amdgcn_fdot2(w[0][k], p, acc0, false);
        acc1 = __builtin_amdgcn_fdot2(w[1][k], p, acc1, false);
        acc2 = __builtin_amdgcn_fdot2(w[2][k], p, acc2, false);
        acc3 = __builtin_amdgcn_fdot2(w[3][k], p, acc3, false);
      }
    }

    // reduce the 4 K-chunk partials: lanes l^1, l^2 share the same jq
    acc0 += __shfl_xor(acc0, 1);  acc0 += __shfl_xor(acc0, 2);
    acc1 += __shfl_xor(acc1, 1);  acc1 += __shfl_xor(acc1, 2);
    acc2 += __shfl_xor(acc2, 1);  acc2 += __shfl_xor(acc2, 2);
    acc3 += __shfl_xor(acc3, 1);  acc3 += __shfl_xor(acc3, 2);

    if (g == 0) {
      float4_t y;
      y[0] = fmaxf(acc0 + xp_cur[0], 0.f);
      y[1] = fmaxf(acc1 + xp_cur[1], 0.f);
      y[2] = fmaxf(acc2 + xp_cur[2], 0.f);
      y[3] = fmaxf(acc3 + xp_cur[3], 0.f);
      *(float4_t*)(out + base + (long)t * HID + j0) = y;   // overwrite xp slot
      half2_t* hw = (half2_t*)(hbuf[cur ^ 1] + j0);
      hw[0] = mkh2(y[0], y[1]);
      hw[1] = mkh2(y[2], y[3]);
    }
    xp_cur = xp_nxt;
    __syncthreads();
  }
}

extern "C" void kernel_launch(void* const* d_in, const int* in_sizes, int n_in,
                              void* d_out, int out_size, void* d_ws, size_t ws_size,
                              hipStream_t stream) {
  const float* x   = (const float*)d_in[0];
  const float* Wxh = (const float*)d_in[1];
  const float* Whh = (const float*)d_in[2];
  const float* bh  = (const float*)d_in[3];
  float* out = (float*)d_out;

  xproj_kernel<<<dim3((BATCH * SEQT) / 64), dim3(256), 0, stream>>>(x, Wxh, bh, out);
  rnn_kernel<<<dim3(BATCH), dim3(256), 0, stream>>>(Whh, out, SEQT);
}

// Round 2
// 1514.346 us; speedup vs baseline: 1.0252x; 1.0252x over previous
//
#include <hip/hip_runtime.h>

#define BATCH 64
#define SEQT  2048
#define DIM   256   // INPUT_SIZE
#define HID   256   // HIDDEN_SIZE

typedef _Float16 half_t;
typedef _Float16 half2_t __attribute__((ext_vector_type(2)));
typedef _Float16 half4_t __attribute__((ext_vector_type(4)));
typedef _Float16 half8_t __attribute__((ext_vector_type(8)));
typedef float    float4_t __attribute__((ext_vector_type(4)));

__device__ __forceinline__ half2_t mkh2(float a, float b) {
  half2_t r; r[0] = (half_t)a; r[1] = (half_t)b; return r;
}
__device__ __forceinline__ half8_t cvt8(float4_t a, float4_t b) {
  half8_t r;
  r[0] = (half_t)a[0]; r[1] = (half_t)a[1]; r[2] = (half_t)a[2]; r[3] = (half_t)a[3];
  r[4] = (half_t)b[0]; r[5] = (half_t)b[1]; r[6] = (half_t)b[2]; r[7] = (half_t)b[3];
  return r;
}
// extract half2 #c from a half8 (c must be a literal -> register aliasing, free)
#define H2X(v, c) __builtin_shufflevector((v), (v), 2*(c), 2*(c)+1)

// ---------------------------------------------------------------------------
// Kernel 0: convert W_xh fp32 -> f16 into d_ws (one-time, trivial).
// ---------------------------------------------------------------------------
__global__ __launch_bounds__(256) void cvt_w_kernel(
    const float* __restrict__ W, half_t* __restrict__ Wh)
{
  const int i = (blockIdx.x * 256 + threadIdx.x) * 4;
  float4_t v = *(const float4_t*)(W + i);
  half4_t o; o[0]=(half_t)v[0]; o[1]=(half_t)v[1]; o[2]=(half_t)v[2]; o[3]=(half_t)v[3];
  *(half4_t*)(Wh + i) = o;
}

// ---------------------------------------------------------------------------
// Kernel 1 (f16-weight path): P[m,n] = sum_k x[m,k]*Wxh[n,k] + bh[n], into out.
// Same verified fragment mapping as round 1; B-frag is now ONE dwordx4 load.
// ---------------------------------------------------------------------------
__global__ __launch_bounds__(256) void xproj_f16_kernel(
    const float* __restrict__ x, const half_t* __restrict__ Wh,
    const float* __restrict__ bh, float* __restrict__ out)
{
  const int lane = threadIdx.x & 63;
  const int wave = threadIdx.x >> 6;
  const int r16  = lane & 15;
  const int kg   = lane >> 4;
  const long m0  = (long)blockIdx.x * 64 + wave * 16;

  half8_t a[8];
  const float* xr = x + (m0 + r16) * (long)DIM + kg * 8;
  #pragma unroll
  for (int kf = 0; kf < 8; ++kf) {
    float4_t x0 = *(const float4_t*)(xr + kf * 32);
    float4_t x1 = *(const float4_t*)(xr + kf * 32 + 4);
    a[kf] = cvt8(x0, x1);
  }

  #pragma unroll 2
  for (int nt = 0; nt < 16; ++nt) {
    const half_t* wr = Wh + (nt * 16 + r16) * (long)DIM + kg * 8;
    float bb = bh[nt * 16 + r16];
    float4_t acc = {bb, bb, bb, bb};
    #pragma unroll
    for (int kf = 0; kf < 8; ++kf) {
      half8_t bfrag = *(const half8_t*)(wr + kf * 32);
      acc = __builtin_amdgcn_mfma_f32_16x16x32_f16(a[kf], bfrag, acc, 0, 0, 0);
    }
    float* op = out + (m0 + kg * 4) * (long)HID + nt * 16 + r16;
    #pragma unroll
    for (int r = 0; r < 4; ++r) op[(long)r * HID] = acc[r];
  }
}

// Fallback (round-1 version) if ws_size can't hold the f16 weights.
__global__ __launch_bounds__(256) void xproj_kernel(
    const float* __restrict__ x, const float* __restrict__ Wxh,
    const float* __restrict__ bh, float* __restrict__ out)
{
  const int lane = threadIdx.x & 63;
  const int wave = threadIdx.x >> 6;
  const int r16  = lane & 15;
  const int kg   = lane >> 4;
  const long m0  = (long)blockIdx.x * 64 + wave * 16;

  half8_t a[8];
  const float* xr = x + (m0 + r16) * (long)DIM + kg * 8;
  #pragma unroll
  for (int kf = 0; kf < 8; ++kf) {
    float4_t x0 = *(const float4_t*)(xr + kf * 32);
    float4_t x1 = *(const float4_t*)(xr + kf * 32 + 4);
    a[kf] = cvt8(x0, x1);
  }
  for (int nt = 0; nt < 16; ++nt) {
    const float* wr = Wxh + (nt * 16 + r16) * (long)DIM + kg * 8;
    float bb = bh[nt * 16 + r16];
    float4_t acc = {bb, bb, bb, bb};
    #pragma unroll
    for (int kf = 0; kf < 8; ++kf) {
      float4_t w0 = *(const float4_t*)(wr + kf * 32);
      float4_t w1 = *(const float4_t*)(wr + kf * 32 + 4);
      acc = __builtin_amdgcn_mfma_f32_16x16x32_f16(a[kf], cvt8(w0, w1), acc, 0, 0, 0);
    }
    float* op = out + (m0 + kg * 4) * (long)HID + nt * 16 + r16;
    #pragma unroll
    for (int r = 0; r < 4; ++r) op[(long)r * HID] = acc[r];
  }
}

// ---------------------------------------------------------------------------
// Kernel 2: recurrence h_t = relu(xp_t + W_hh h_{t-1}).  One block per batch
// chain, 256 threads; thread j owns output j for all t:
//   - W_hh row j lives in 128 VGPRs as f16 (static indexing only)
//   - h double-buffered in LDS f16; reads are wave-broadcast (same address
//     across lanes -> conflict-free), 32x ds_read_b128 per step
//   - NO cross-thread reduction (no shuffles)
//   - raw `s_waitcnt lgkmcnt(0); s_barrier` per step: global xp loads and y
//     stores stay IN FLIGHT across barriers (no vmcnt(0) drain).  xp is
//     prefetched 4 steps deep with statically-unrolled rotating registers;
//     the compiler's own counted vmcnt at the use point does the rest.
// ---------------------------------------------------------------------------
#define RNN_BAR() asm volatile("s_waitcnt lgkmcnt(0)\n\ts_barrier" ::: "memory")

#define RNN_STEP(U, XQ)                                                        \
  {                                                                            \
    const int t = t4 + (U);                                                    \
    float xnew = 0.f;                                                          \
    if (t + 4 < T) xnew = outj[(long)(t + 4) * HID];                           \
    const half8_t* hp = (const half8_t*)hbuf[(U) & 1];                         \
    float a0 = 0.f, a1 = 0.f, a2 = 0.f, a3 = 0.f;                              \
    _Pragma("unroll")                                                          \
    for (int s = 0; s < 32; ++s) {                                             \
      half8_t hv = hp[s];                                                      \
      a0 = __builtin_amdgcn_fdot2(H2X(w8[s], 0), H2X(hv, 0), a0, false);       \
      a1 = __builtin_amdgcn_fdot2(H2X(w8[s], 1), H2X(hv, 1), a1, false);       \
      a2 = __builtin_amdgcn_fdot2(H2X(w8[s], 2), H2X(hv, 2), a2, false);       \
      a3 = __builtin_amdgcn_fdot2(H2X(w8[s], 3), H2X(hv, 3), a3, false);       \
    }                                                                          \
    float y = fmaxf((a0 + a1) + (a2 + a3) + (XQ), 0.f);                        \
    outj[(long)t * HID] = y;                                                   \
    hbuf[((U) & 1) ^ 1][tid] = (half_t)y;                                      \
    XQ = xnew;                                                                 \
    RNN_BAR();                                                                 \
  }

__global__ __launch_bounds__(256, 1) void rnn_kernel(
    const float* __restrict__ Whh, float* __restrict__ out, int T)
{
  __shared__ alignas(16) half_t hbuf[2][HID];
  const int tid = threadIdx.x;
  float* outj = out + (long)blockIdx.x * SEQT * HID + tid;

  // W_hh row `tid` -> 128 f16 VGPRs (32 x half8), fp32->f16 once.
  half8_t w8[32];
  {
    const float* wr = Whh + (long)tid * HID;
    #pragma unroll
    for (int s = 0; s < 32; ++s) {
      float4_t v0 = *(const float4_t*)(wr + s * 8);
      float4_t v1 = *(const float4_t*)(wr + s * 8 + 4);
      w8[s] = cvt8(v0, v1);
    }
  }

  hbuf[0][tid] = (half_t)0.f;   // h_0 = 0 (hbuf[1] written at t=0 before use)

  // 4-deep xp prefetch pipeline (named regs; loop unrolled x4 => static idx)
  float xq0 = outj[0L * HID];
  float xq1 = outj[1L * HID];
  float xq2 = outj[2L * HID];
  float xq3 = outj[3L * HID];
  RNN_BAR();

  #pragma unroll 1
  for (int t4 = 0; t4 < T; t4 += 4) {
    RNN_STEP(0, xq0)
    RNN_STEP(1, xq1)
    RNN_STEP(2, xq2)
    RNN_STEP(3, xq3)
  }
}

extern "C" void kernel_launch(void* const* d_in, const int* in_sizes, int n_in,
                              void* d_out, int out_size, void* d_ws, size_t ws_size,
                              hipStream_t stream) {
  const float* x   = (const float*)d_in[0];
  const float* Wxh = (const float*)d_in[1];
  const float* Whh = (const float*)d_in[2];
  const float* bh  = (const float*)d_in[3];
  float* out = (float*)d_out;

  if (ws_size >= (size_t)(DIM * HID * sizeof(half_t))) {
    half_t* Wh = (half_t*)d_ws;
    cvt_w_kernel<<<dim3((DIM * HID) / 1024), dim3(256), 0, stream>>>(Wxh, Wh);
    xproj_f16_kernel<<<dim3((BATCH * SEQT) / 64), dim3(256), 0, stream>>>(x, Wh, bh, out);
  } else {
    xproj_kernel<<<dim3((BATCH * SEQT) / 64), dim3(256), 0, stream>>>(x, Wxh, bh, out);
  }
  rnn_kernel<<<dim3(BATCH), dim3(256), 0, stream>>>(Whh, out, SEQT);
}

// Round 4
// 1244.686 us; speedup vs baseline: 1.2473x; 1.2166x over previous
//
#include <hip/hip_runtime.h>

#define BATCH 64
#define SEQT  2048
#define DIM   256   // INPUT_SIZE
#define HID   256   // HIDDEN_SIZE

typedef _Float16 half_t;
typedef _Float16 half2_t __attribute__((ext_vector_type(2)));
typedef _Float16 half4_t __attribute__((ext_vector_type(4)));
typedef _Float16 half8_t __attribute__((ext_vector_type(8)));
typedef float    float4_t __attribute__((ext_vector_type(4)));

__device__ __forceinline__ half8_t cvt8(float4_t a, float4_t b) {
  half8_t r;
  r[0] = (half_t)a[0]; r[1] = (half_t)a[1]; r[2] = (half_t)a[2]; r[3] = (half_t)a[3];
  r[4] = (half_t)b[0]; r[5] = (half_t)b[1]; r[6] = (half_t)b[2]; r[7] = (half_t)b[3];
  return r;
}
// extract half2 #c from a half8 (c MUST be a literal -> register aliasing)
#define H2X(v, c) __builtin_shufflevector((v), (v), 2*(c), 2*(c)+1)

// butterfly add via DPP (pure VALU).  CTRL as template param (ICE required).
// 0xB1 = quad_perm [1,0,3,2] (lane^1); 0x4E = quad_perm [2,3,0,1] (lane^2);
// 0x141 = row_half_mirror (lane XOR 7 within 8 -> acts as lane^4 once bits
// 0,1 are already reduced).
template<int CTRL>
__device__ __forceinline__ float dpp_add(float a) {
  int t = __builtin_amdgcn_mov_dpp(__builtin_bit_cast(int, a), CTRL, 0xF, 0xF, true);
  return a + __builtin_bit_cast(float, t);
}

// ---------------------------------------------------------------------------
// Kernel 0: convert W_xh fp32 -> f16 into d_ws (one-time, trivial).
// ---------------------------------------------------------------------------
__global__ __launch_bounds__(256) void cvt_w_kernel(
    const float* __restrict__ W, half_t* __restrict__ Wh)
{
  const int i = (blockIdx.x * 256 + threadIdx.x) * 4;
  float4_t v = *(const float4_t*)(W + i);
  half4_t o; o[0]=(half_t)v[0]; o[1]=(half_t)v[1]; o[2]=(half_t)v[2]; o[3]=(half_t)v[3];
  *(half4_t*)(Wh + i) = o;
}

// ---------------------------------------------------------------------------
// Kernel 1: P[m,n] = sum_k x[m,k]*Wxh[n,k] + bh[n] -> out (fp32), MFMA f16.
// ---------------------------------------------------------------------------
__global__ __launch_bounds__(256) void xproj_f16_kernel(
    const float* __restrict__ x, const half_t* __restrict__ Wh,
    const float* __restrict__ bh, float* __restrict__ out)
{
  const int lane = threadIdx.x & 63;
  const int wave = threadIdx.x >> 6;
  const int r16  = lane & 15;
  const int kg   = lane >> 4;
  const long m0  = (long)blockIdx.x * 64 + wave * 16;

  half8_t a[8];
  const float* xr = x + (m0 + r16) * (long)DIM + kg * 8;
  #pragma unroll
  for (int kf = 0; kf < 8; ++kf) {
    float4_t x0 = *(const float4_t*)(xr + kf * 32);
    float4_t x1 = *(const float4_t*)(xr + kf * 32 + 4);
    a[kf] = cvt8(x0, x1);
  }

  #pragma unroll 2
  for (int nt = 0; nt < 16; ++nt) {
    const half_t* wr = Wh + (nt * 16 + r16) * (long)DIM + kg * 8;
    float bb = bh[nt * 16 + r16];
    float4_t acc = {bb, bb, bb, bb};
    #pragma unroll
    for (int kf = 0; kf < 8; ++kf) {
      half8_t bfrag = *(const half8_t*)(wr + kf * 32);
      acc = __builtin_amdgcn_mfma_f32_16x16x32_f16(a[kf], bfrag, acc, 0, 0, 0);
    }
    float* op = out + (m0 + kg * 4) * (long)HID + nt * 16 + r16;
    #pragma unroll
    for (int r = 0; r < 4; ++r) op[(long)r * HID] = acc[r];
  }
}

__global__ __launch_bounds__(256) void xproj_kernel(
    const float* __restrict__ x, const float* __restrict__ Wxh,
    const float* __restrict__ bh, float* __restrict__ out)
{
  const int lane = threadIdx.x & 63;
  const int wave = threadIdx.x >> 6;
  const int r16  = lane & 15;
  const int kg   = lane >> 4;
  const long m0  = (long)blockIdx.x * 64 + wave * 16;

  half8_t a[8];
  const float* xr = x + (m0 + r16) * (long)DIM + kg * 8;
  #pragma unroll
  for (int kf = 0; kf < 8; ++kf) {
    float4_t x0 = *(const float4_t*)(xr + kf * 32);
    float4_t x1 = *(const float4_t*)(xr + kf * 32 + 4);
    a[kf] = cvt8(x0, x1);
  }
  for (int nt = 0; nt < 16; ++nt) {
    const float* wr = Wxh + (nt * 16 + r16) * (long)DIM + kg * 8;
    float bb = bh[nt * 16 + r16];
    float4_t acc = {bb, bb, bb, bb};
    #pragma unroll
    for (int kf = 0; kf < 8; ++kf) {
      float4_t w0 = *(const float4_t*)(wr + kf * 32);
      float4_t w1 = *(const float4_t*)(wr + kf * 32 + 4);
      acc = __builtin_amdgcn_mfma_f32_16x16x32_f16(a[kf], cvt8(w0, w1), acc, 0, 0, 0);
    }
    float* op = out + (m0 + kg * 4) * (long)HID + nt * 16 + r16;
    #pragma unroll
    for (int r = 0; r < 4; ++r) op[(long)r * HID] = acc[r];
  }
}

// ---------------------------------------------------------------------------
// Kernel 2 (v4): h_t = relu(xp_t + W_hh h_{t-1}).  One block per chain.
// 256 threads; lane l of wave w:
//   g  = l & 7        K-chunk id (8 chunks of 32 columns)
//   jo = w*8 + (l>>3) output octet: rows [8jo, 8jo+8)
// Thread: 8 partial outputs over its 32-wide K chunk = 128 fdot2.
// Reduce over the 8 g's = 3 DPP butterflies (l^1, l^2, l^4-equivalent) —
// pure VALU, no LDS/shuffle traffic, no cross-half ops.
// Active lanes (l&7)==0 (8/wave) then own 8 CONSECUTIVE outputs j0=8jo:
// 2x float4 xp/out, one half8 LDS h write.
// h in LDS: chunk g at byte 80g (16B pad) -> the 8 broadcast ds_read_b128
// addresses perfectly partition all 32 banks.  1 barrier/step, lgkmcnt-only
// (global loads/stores stay in flight); xp prefetched 4 steps deep in
// named registers (all static indexing).
// ---------------------------------------------------------------------------
#define RNN_BAR() asm volatile("s_waitcnt lgkmcnt(0)\n\ts_barrier" ::: "memory")

#define RNN_STEP(U, XQA, XQB)                                                  \
  {                                                                            \
    const int t = t4 + (U);                                                    \
    half8_t hv[4];                                                             \
    _Pragma("unroll")                                                          \
    for (int s = 0; s < 4; ++s)                                                \
      hv[s] = *(const half8_t*)(hraw[(U) & 1] + rb + 16 * s);                  \
    float a[8] = {0.f, 0.f, 0.f, 0.f, 0.f, 0.f, 0.f, 0.f};                     \
    _Pragma("unroll")                                                          \
    for (int s = 0; s < 4; ++s) {                                              \
      _Pragma("unroll")                                                        \
      for (int i = 0; i < 8; ++i) {                                            \
        a[i] = __builtin_amdgcn_fdot2(H2X(w8[i][s], 0), H2X(hv[s], 0), a[i], false); \
        a[i] = __builtin_amdgcn_fdot2(H2X(w8[i][s], 1), H2X(hv[s], 1), a[i], false); \
        a[i] = __builtin_amdgcn_fdot2(H2X(w8[i][s], 2), H2X(hv[s], 2), a[i], false); \
        a[i] = __builtin_amdgcn_fdot2(H2X(w8[i][s], 3), H2X(hv[s], 3), a[i], false); \
      }                                                                        \
    }                                                                          \
    _Pragma("unroll")                                                          \
    for (int i = 0; i < 8; ++i) {                                              \
      a[i] = dpp_add<0xB1>(a[i]);   /* + lane^1 */                             \
      a[i] = dpp_add<0x4E>(a[i]);   /* + lane^2 */                             \
      a[i] = dpp_add<0x141>(a[i]);  /* row_half_mirror == + lane^4 here */     \
    }                                                                          \
    if (act) {                                                                 \
      float4_t y0, y1;                                                         \
      y0[0] = fmaxf(a[0] + (XQA)[0], 0.f); y0[1] = fmaxf(a[1] + (XQA)[1], 0.f);\
      y0[2] = fmaxf(a[2] + (XQA)[2], 0.f); y0[3] = fmaxf(a[3] + (XQA)[3], 0.f);\
      y1[0] = fmaxf(a[4] + (XQB)[0], 0.f); y1[1] = fmaxf(a[5] + (XQB)[1], 0.f);\
      y1[2] = fmaxf(a[6] + (XQB)[2], 0.f); y1[3] = fmaxf(a[7] + (XQB)[3], 0.f);\
      *(float4_t*)(outp + (long)t * HID)     = y0;                             \
      *(float4_t*)(outp + (long)t * HID + 4) = y1;                             \
      half8_t hy;                                                              \
      hy[0] = (half_t)y0[0]; hy[1] = (half_t)y0[1];                            \
      hy[2] = (half_t)y0[2]; hy[3] = (half_t)y0[3];                            \
      hy[4] = (half_t)y1[0]; hy[5] = (half_t)y1[1];                            \
      hy[6] = (half_t)y1[2]; hy[7] = (half_t)y1[3];                            \
      *(half8_t*)(hraw[((U) & 1) ^ 1] + wb) = hy;                              \
      if (t + 4 < T) {                                                         \
        XQA = *(const float4_t*)(outp + (long)(t + 4) * HID);                  \
        XQB = *(const float4_t*)(outp + (long)(t + 4) * HID + 4);              \
      }                                                                        \
    }                                                                          \
    RNN_BAR();                                                                 \
  }

__global__ __launch_bounds__(256, 1) void rnn_kernel(
    const float* __restrict__ Whh, float* __restrict__ out, int T)
{
  // 8 chunks x (64B data + 16B pad), double buffered
  __shared__ alignas(128) unsigned char hraw[2][8 * 80];

  const int tid = threadIdx.x;
  const int l   = tid & 63;
  const int w   = tid >> 6;
  const int g   = l & 7;                 // K-chunk: columns [32g, 32g+32)
  const int jo  = w * 8 + (l >> 3);      // output octet: rows [8jo, 8jo+8)
  const bool act = (l & 7) == 0;
  const int j0  = jo * 8;
  const int rb  = g * 80;                          // LDS read base (bytes)
  const int wb  = (j0 >> 5) * 80 + (j0 & 31) * 2;  // LDS write base (bytes)
  float* outp = out + (long)blockIdx.x * SEQT * HID + j0;

  // W_hh[8jo+i][32g + 8s .. +8] -> w8[i][s]  (128 VGPRs, static indexing)
  half8_t w8[8][4];
  #pragma unroll
  for (int i = 0; i < 8; ++i) {
    const float* wr = Whh + (long)(j0 + i) * HID + g * 32;
    #pragma unroll
    for (int s = 0; s < 4; ++s) {
      float4_t v0 = *(const float4_t*)(wr + s * 8);
      float4_t v1 = *(const float4_t*)(wr + s * 8 + 4);
      w8[i][s] = cvt8(v0, v1);
    }
  }

  // h_0 = 0 (covers data+pads of buffer 0)
  if (tid < 160) ((float*)hraw[0])[tid] = 0.f;

  // 4-deep xp prefetch (named registers -> static indexing)
  float4_t xq0a = {0,0,0,0}, xq0b = {0,0,0,0}, xq1a = {0,0,0,0}, xq1b = {0,0,0,0};
  float4_t xq2a = {0,0,0,0}, xq2b = {0,0,0,0}, xq3a = {0,0,0,0}, xq3b = {0,0,0,0};
  if (act) {
    xq0a = *(const float4_t*)(outp + 0L * HID); xq0b = *(const float4_t*)(outp + 0L * HID + 4);
    xq1a = *(const float4_t*)(outp + 1L * HID); xq1b = *(const float4_t*)(outp + 1L * HID + 4);
    xq2a = *(const float4_t*)(outp + 2L * HID); xq2b = *(const float4_t*)(outp + 2L * HID + 4);
    xq3a = *(const float4_t*)(outp + 3L * HID); xq3b = *(const float4_t*)(outp + 3L * HID + 4);
  }
  RNN_BAR();

  #pragma unroll 1
  for (int t4 = 0; t4 < T; t4 += 4) {
    RNN_STEP(0, xq0a, xq0b)
    RNN_STEP(1, xq1a, xq1b)
    RNN_STEP(2, xq2a, xq2b)
    RNN_STEP(3, xq3a, xq3b)
  }
}

extern "C" void kernel_launch(void* const* d_in, const int* in_sizes, int n_in,
                              void* d_out, int out_size, void* d_ws, size_t ws_size,
                              hipStream_t stream) {
  const float* x   = (const float*)d_in[0];
  const float* Wxh = (const float*)d_in[1];
  const float* Whh = (const float*)d_in[2];
  const float* bh  = (const float*)d_in[3];
  float* out = (float*)d_out;

  if (ws_size >= (size_t)(DIM * HID * sizeof(half_t))) {
    half_t* Wh = (half_t*)d_ws;
    cvt_w_kernel<<<dim3((DIM * HID) / 1024), dim3(256), 0, stream>>>(Wxh, Wh);
    xproj_f16_kernel<<<dim3((BATCH * SEQT) / 64), dim3(256), 0, stream>>>(x, Wh, bh, out);
  } else {
    xproj_kernel<<<dim3((BATCH * SEQT) / 64), dim3(256), 0, stream>>>(x, Wxh, bh, out);
  }
  rnn_kernel<<<dim3(BATCH), dim3(256), 0, stream>>>(Whh, out, SEQT);
}

// Round 5
// 1018.205 us; speedup vs baseline: 1.5248x; 1.2224x over previous
//
#include <hip/hip_runtime.h>

#define BATCH 64
#define SEQT  2048
#define DIM   256   // INPUT_SIZE
#define HID   256   // HIDDEN_SIZE

typedef _Float16 half_t;
typedef _Float16 half2_t __attribute__((ext_vector_type(2)));
typedef _Float16 half4_t __attribute__((ext_vector_type(4)));
typedef _Float16 half8_t __attribute__((ext_vector_type(8)));
typedef float    float4_t __attribute__((ext_vector_type(4)));

__device__ __forceinline__ half8_t cvt8(float4_t a, float4_t b) {
  half8_t r;
  r[0] = (half_t)a[0]; r[1] = (half_t)a[1]; r[2] = (half_t)a[2]; r[3] = (half_t)a[3];
  r[4] = (half_t)b[0]; r[5] = (half_t)b[1]; r[6] = (half_t)b[2]; r[7] = (half_t)b[3];
  return r;
}
// extract half2 #c from a half8 (c MUST be a literal -> register aliasing)
#define H2X(v, c) __builtin_shufflevector((v), (v), 2*(c), 2*(c)+1)

// DPP lane-move (pure VALU).  0xB1 = quad_perm lane^1; 0x4E = quad_perm
// lane^2; 0x141 = row_half_mirror = lane^7 within each aligned 8-lane group.
template<int CTRL>
__device__ __forceinline__ float dpp_mov(float a) {
  int t = __builtin_amdgcn_mov_dpp(__builtin_bit_cast(int, a), CTRL, 0xF, 0xF, true);
  return __builtin_bit_cast(float, t);
}

// ---------------------------------------------------------------------------
// Kernel 0: convert W_xh fp32 -> f16 into d_ws (one-time, trivial).
// ---------------------------------------------------------------------------
__global__ __launch_bounds__(256) void cvt_w_kernel(
    const float* __restrict__ W, half_t* __restrict__ Wh)
{
  const int i = (blockIdx.x * 256 + threadIdx.x) * 4;
  float4_t v = *(const float4_t*)(W + i);
  half4_t o; o[0]=(half_t)v[0]; o[1]=(half_t)v[1]; o[2]=(half_t)v[2]; o[3]=(half_t)v[3];
  *(half4_t*)(Wh + i) = o;
}

// ---------------------------------------------------------------------------
// Kernel 1: P[m,n] = sum_k x[m,k]*Wxh[n,k] + bh[n] -> out (fp32), MFMA f16.
// ---------------------------------------------------------------------------
__global__ __launch_bounds__(256) void xproj_f16_kernel(
    const float* __restrict__ x, const half_t* __restrict__ Wh,
    const float* __restrict__ bh, float* __restrict__ out)
{
  const int lane = threadIdx.x & 63;
  const int wave = threadIdx.x >> 6;
  const int r16  = lane & 15;
  const int kg   = lane >> 4;
  const long m0  = (long)blockIdx.x * 64 + wave * 16;

  half8_t a[8];
  const float* xr = x + (m0 + r16) * (long)DIM + kg * 8;
  #pragma unroll
  for (int kf = 0; kf < 8; ++kf) {
    float4_t x0 = *(const float4_t*)(xr + kf * 32);
    float4_t x1 = *(const float4_t*)(xr + kf * 32 + 4);
    a[kf] = cvt8(x0, x1);
  }

  #pragma unroll 2
  for (int nt = 0; nt < 16; ++nt) {
    const half_t* wr = Wh + (nt * 16 + r16) * (long)DIM + kg * 8;
    float bb = bh[nt * 16 + r16];
    float4_t acc = {bb, bb, bb, bb};
    #pragma unroll
    for (int kf = 0; kf < 8; ++kf) {
      half8_t bfrag = *(const half8_t*)(wr + kf * 32);
      acc = __builtin_amdgcn_mfma_f32_16x16x32_f16(a[kf], bfrag, acc, 0, 0, 0);
    }
    float* op = out + (m0 + kg * 4) * (long)HID + nt * 16 + r16;
    #pragma unroll
    for (int r = 0; r < 4; ++r) op[(long)r * HID] = acc[r];
  }
}

__global__ __launch_bounds__(256) void xproj_kernel(
    const float* __restrict__ x, const float* __restrict__ Wxh,
    const float* __restrict__ bh, float* __restrict__ out)
{
  const int lane = threadIdx.x & 63;
  const int wave = threadIdx.x >> 6;
  const int r16  = lane & 15;
  const int kg   = lane >> 4;
  const long m0  = (long)blockIdx.x * 64 + wave * 16;

  half8_t a[8];
  const float* xr = x + (m0 + r16) * (long)DIM + kg * 8;
  #pragma unroll
  for (int kf = 0; kf < 8; ++kf) {
    float4_t x0 = *(const float4_t*)(xr + kf * 32);
    float4_t x1 = *(const float4_t*)(xr + kf * 32 + 4);
    a[kf] = cvt8(x0, x1);
  }
  for (int nt = 0; nt < 16; ++nt) {
    const float* wr = Wxh + (nt * 16 + r16) * (long)DIM + kg * 8;
    float bb = bh[nt * 16 + r16];
    float4_t acc = {bb, bb, bb, bb};
    #pragma unroll
    for (int kf = 0; kf < 8; ++kf) {
      float4_t w0 = *(const float4_t*)(wr + kf * 32);
      float4_t w1 = *(const float4_t*)(wr + kf * 32 + 4);
      acc = __builtin_amdgcn_mfma_f32_16x16x32_f16(a[kf], cvt8(w0, w1), acc, 0, 0, 0);
    }
    float* op = out + (m0 + kg * 4) * (long)HID + nt * 16 + r16;
    #pragma unroll
    for (int r = 0; r < 4; ++r) op[(long)r * HID] = acc[r];
  }
}

// ---------------------------------------------------------------------------
// Kernel 2 (v5): h_t = relu(xp_t + W_hh h_{t-1}).  One block per chain.
// lane l of wave w:  g = l&7 (K-chunk of 32), octet jo = w*8 + (l>>3).
// Thread: 8 partials (outputs 8jo..8jo+7) over chunk g = 128 fdot2.
// REDUCE-SCATTER (3 DPP exchange stages: l^7 mirror, l^1, l^2) leaves lane l
// with the FULL sum of output 64w + l  ->  branch-free, fully-coalesced
// epilogue: 1 fmax, 1 dword store/lane, 1 ds_write_b16, 1 dword xp load/lane.
// xp prefetch is 4 deep with a wave-UNIFORM clamped address (no divergent
// branches anywhere in the loop -> deterministic counted vmcnt; globals stay
// in flight across the lgkmcnt-only barrier).
// LDS h: chunk g at byte 80g; per ds_read_b128 the 8 groups hit 8 disjoint
// bank quads (20g mod 32 cycles all multiples of 4) -> conflict-free.
// ---------------------------------------------------------------------------
#define RNN_BAR() asm volatile("s_waitcnt lgkmcnt(0)\n\ts_barrier" ::: "memory")

#define RNN_STEP(U, XQ)                                                        \
  {                                                                            \
    const int t = t4 + (U);                                                    \
    /* prefetch xp for step t+4 (uniform clamped addr, always executes) */     \
    const int tp = (t + 4 < T) ? (t + 4) : (T - 1);                            \
    float xnew = outp[(long)tp * HID];                                         \
    half8_t hv[4];                                                             \
    _Pragma("unroll")                                                          \
    for (int s = 0; s < 4; ++s)                                                \
      hv[s] = *(const half8_t*)(hraw[(U) & 1] + rb + 16 * s);                  \
    float a[8] = {0.f, 0.f, 0.f, 0.f, 0.f, 0.f, 0.f, 0.f};                     \
    _Pragma("unroll")                                                          \
    for (int s = 0; s < 4; ++s) {                                              \
      _Pragma("unroll")                                                        \
      for (int i = 0; i < 8; ++i) {                                            \
        a[i] = __builtin_amdgcn_fdot2(H2X(w8[i][s], 0), H2X(hv[s], 0), a[i], false); \
        a[i] = __builtin_amdgcn_fdot2(H2X(w8[i][s], 1), H2X(hv[s], 1), a[i], false); \
        a[i] = __builtin_amdgcn_fdot2(H2X(w8[i][s], 2), H2X(hv[s], 2), a[i], false); \
        a[i] = __builtin_amdgcn_fdot2(H2X(w8[i][s], 3), H2X(hv[s], 3), a[i], false); \
      }                                                                        \
    }                                                                          \
    /* reduce-scatter: lane l ends with full sum of output index (l&7) */      \
    float b0, b1, b2, b3, c0, c1, fin;                                         \
    {  /* stage A: partner l^7, keep indices with bit2 == (l&4) */             \
      float r0 = s4 ? a[0] : a[4];                                             \
      float r1 = s4 ? a[1] : a[5];                                             \
      float r2 = s4 ? a[2] : a[6];                                             \
      float r3 = s4 ? a[3] : a[7];                                             \
      b0 = (s4 ? a[4] : a[0]) + dpp_mov<0x141>(r0);                            \
      b1 = (s4 ? a[5] : a[1]) + dpp_mov<0x141>(r1);                            \
      b2 = (s4 ? a[6] : a[2]) + dpp_mov<0x141>(r2);                            \
      b3 = (s4 ? a[7] : a[3]) + dpp_mov<0x141>(r3);                            \
    }                                                                          \
    {  /* stage B: partner l^1, keep bit0 == (l&1) */                          \
      float r0 = s1 ? b0 : b1;                                                 \
      float r1 = s1 ? b2 : b3;                                                 \
      c0 = (s1 ? b1 : b0) + dpp_mov<0xB1>(r0);                                 \
      c1 = (s1 ? b3 : b2) + dpp_mov<0xB1>(r1);                                 \
    }                                                                          \
    {  /* stage C: partner l^2, keep bit1 == (l&2) */                          \
      float r = s2 ? c0 : c1;                                                  \
      fin = (s2 ? c1 : c0) + dpp_mov<0x4E>(r);                                 \
    }                                                                          \
    float y = fmaxf(fin + (XQ), 0.f);                                          \
    outp[(long)t * HID] = y;                                                   \
    *(half_t*)(hraw[((U) & 1) ^ 1] + hwb) = (half_t)y;                         \
    XQ = xnew;                                                                 \
    RNN_BAR();                                                                 \
  }

__global__ __launch_bounds__(256, 1) void rnn_kernel(
    const float* __restrict__ Whh, float* __restrict__ out, int T)
{
  // 8 chunks x (64B data + 16B pad), double buffered
  __shared__ alignas(128) unsigned char hraw[2][8 * 80];

  const int tid = threadIdx.x;
  const int l   = tid & 63;
  const int w   = tid >> 6;
  const int g   = l & 7;                 // K-chunk: columns [32g, 32g+32)
  const int jo  = w * 8 + (l >> 3);      // partials for rows [8jo, 8jo+8)
  const int j0  = jo * 8;
  const int rb  = g * 80;                // LDS read base (bytes)
  const int jown = w * 64 + l;           // output row this lane OWNS post-reduce
  const int hwb = ((jown >> 5) * 80 + (jown & 31) * 2);  // LDS write byte
  const bool s4 = (l & 4) != 0;
  const bool s1 = (l & 1) != 0;
  const bool s2 = (l & 2) != 0;
  float* outp = out + (long)blockIdx.x * SEQT * HID + jown;

  // W_hh[j0+i][32g + 8s .. +8] -> w8[i][s]  (128 VGPRs, static indexing)
  half8_t w8[8][4];
  #pragma unroll
  for (int i = 0; i < 8; ++i) {
    const float* wr = Whh + (long)(j0 + i) * HID + g * 32;
    #pragma unroll
    for (int s = 0; s < 4; ++s) {
      float4_t v0 = *(const float4_t*)(wr + s * 8);
      float4_t v1 = *(const float4_t*)(wr + s * 8 + 4);
      w8[i][s] = cvt8(v0, v1);
    }
  }

  // h_0 = 0 (covers data+pads of buffer 0)
  if (tid < 160) ((float*)hraw[0])[tid] = 0.f;

  // 4-deep xp prefetch (named registers -> static indexing), all lanes
  float xq0 = outp[0L * HID];
  float xq1 = outp[1L * HID];
  float xq2 = outp[2L * HID];
  float xq3 = outp[3L * HID];
  RNN_BAR();

  #pragma unroll 1
  for (int t4 = 0; t4 < T; t4 += 4) {
    RNN_STEP(0, xq0)
    RNN_STEP(1, xq1)
    RNN_STEP(2, xq2)
    RNN_STEP(3, xq3)
  }
}

extern "C" void kernel_launch(void* const* d_in, const int* in_sizes, int n_in,
                              void* d_out, int out_size, void* d_ws, size_t ws_size,
                              hipStream_t stream) {
  const float* x   = (const float*)d_in[0];
  const float* Wxh = (const float*)d_in[1];
  const float* Whh = (const float*)d_in[2];
  const float* bh  = (const float*)d_in[3];
  float* out = (float*)d_out;

  if (ws_size >= (size_t)(DIM * HID * sizeof(half_t))) {
    half_t* Wh = (half_t*)d_ws;
    cvt_w_kernel<<<dim3((DIM * HID) / 1024), dim3(256), 0, stream>>>(Wxh, Wh);
    xproj_f16_kernel<<<dim3((BATCH * SEQT) / 64), dim3(256), 0, stream>>>(x, Wh, bh, out);
  } else {
    xproj_kernel<<<dim3((BATCH * SEQT) / 64), dim3(256), 0, stream>>>(x, Wxh, bh, out);
  }
  rnn_kernel<<<dim3(BATCH), dim3(256), 0, stream>>>(Whh, out, SEQT);
}

// Round 6
// 989.661 us; speedup vs baseline: 1.5687x; 1.0288x over previous
//
#include <hip/hip_runtime.h>

#define BATCH 64
#define SEQT  2048
#define DIM   256   // INPUT_SIZE
#define HID   256   // HIDDEN_SIZE

typedef _Float16 half_t;
typedef _Float16 half2_t __attribute__((ext_vector_type(2)));
typedef _Float16 half4_t __attribute__((ext_vector_type(4)));
typedef _Float16 half8_t __attribute__((ext_vector_type(8)));
typedef float    float4_t __attribute__((ext_vector_type(4)));

__device__ __forceinline__ half8_t cvt8(float4_t a, float4_t b) {
  half8_t r;
  r[0] = (half_t)a[0]; r[1] = (half_t)a[1]; r[2] = (half_t)a[2]; r[3] = (half_t)a[3];
  r[4] = (half_t)b[0]; r[5] = (half_t)b[1]; r[6] = (half_t)b[2]; r[7] = (half_t)b[3];
  return r;
}
// extract half2 #c from a half8 (c MUST be a literal -> register aliasing)
#define H2X(v, c) __builtin_shufflevector((v), (v), 2*(c), 2*(c)+1)

// DPP lane-move (pure VALU).  0xB1 = quad_perm lane^1; 0x4E = quad_perm
// lane^2; 0x141 = row_half_mirror = lane^7 within each aligned 8-lane group.
template<int CTRL>
__device__ __forceinline__ float dpp_mov(float a) {
  int t = __builtin_amdgcn_mov_dpp(__builtin_bit_cast(int, a), CTRL, 0xF, 0xF, true);
  return __builtin_bit_cast(float, t);
}

// ---------------------------------------------------------------------------
// Kernel 0: convert W_xh fp32 -> f16 into d_ws (one-time, trivial).
// ---------------------------------------------------------------------------
__global__ __launch_bounds__(256) void cvt_w_kernel(
    const float* __restrict__ W, half_t* __restrict__ Wh)
{
  const int i = (blockIdx.x * 256 + threadIdx.x) * 4;
  float4_t v = *(const float4_t*)(W + i);
  half4_t o; o[0]=(half_t)v[0]; o[1]=(half_t)v[1]; o[2]=(half_t)v[2]; o[3]=(half_t)v[3];
  *(half4_t*)(Wh + i) = o;
}

// ---------------------------------------------------------------------------
// Kernel 1: P[m,n] = sum_k x[m,k]*Wxh[n,k] + bh[n] -> out (fp32), MFMA f16.
// ---------------------------------------------------------------------------
__global__ __launch_bounds__(256) void xproj_f16_kernel(
    const float* __restrict__ x, const half_t* __restrict__ Wh,
    const float* __restrict__ bh, float* __restrict__ out)
{
  const int lane = threadIdx.x & 63;
  const int wave = threadIdx.x >> 6;
  const int r16  = lane & 15;
  const int kg   = lane >> 4;
  const long m0  = (long)blockIdx.x * 64 + wave * 16;

  half8_t a[8];
  const float* xr = x + (m0 + r16) * (long)DIM + kg * 8;
  #pragma unroll
  for (int kf = 0; kf < 8; ++kf) {
    float4_t x0 = *(const float4_t*)(xr + kf * 32);
    float4_t x1 = *(const float4_t*)(xr + kf * 32 + 4);
    a[kf] = cvt8(x0, x1);
  }

  #pragma unroll 2
  for (int nt = 0; nt < 16; ++nt) {
    const half_t* wr = Wh + (nt * 16 + r16) * (long)DIM + kg * 8;
    float bb = bh[nt * 16 + r16];
    float4_t acc = {bb, bb, bb, bb};
    #pragma unroll
    for (int kf = 0; kf < 8; ++kf) {
      half8_t bfrag = *(const half8_t*)(wr + kf * 32);
      acc = __builtin_amdgcn_mfma_f32_16x16x32_f16(a[kf], bfrag, acc, 0, 0, 0);
    }
    float* op = out + (m0 + kg * 4) * (long)HID + nt * 16 + r16;
    #pragma unroll
    for (int r = 0; r < 4; ++r) op[(long)r * HID] = acc[r];
  }
}

__global__ __launch_bounds__(256) void xproj_kernel(
    const float* __restrict__ x, const float* __restrict__ Wxh,
    const float* __restrict__ bh, float* __restrict__ out)
{
  const int lane = threadIdx.x & 63;
  const int wave = threadIdx.x >> 6;
  const int r16  = lane & 15;
  const int kg   = lane >> 4;
  const long m0  = (long)blockIdx.x * 64 + wave * 16;

  half8_t a[8];
  const float* xr = x + (m0 + r16) * (long)DIM + kg * 8;
  #pragma unroll
  for (int kf = 0; kf < 8; ++kf) {
    float4_t x0 = *(const float4_t*)(xr + kf * 32);
    float4_t x1 = *(const float4_t*)(xr + kf * 32 + 4);
    a[kf] = cvt8(x0, x1);
  }
  for (int nt = 0; nt < 16; ++nt) {
    const float* wr = Wxh + (nt * 16 + r16) * (long)DIM + kg * 8;
    float bb = bh[nt * 16 + r16];
    float4_t acc = {bb, bb, bb, bb};
    #pragma unroll
    for (int kf = 0; kf < 8; ++kf) {
      float4_t w0 = *(const float4_t*)(wr + kf * 32);
      float4_t w1 = *(const float4_t*)(wr + kf * 32 + 4);
      acc = __builtin_amdgcn_mfma_f32_16x16x32_f16(a[kf], cvt8(w0, w1), acc, 0, 0, 0);
    }
    float* op = out + (m0 + kg * 4) * (long)HID + nt * 16 + r16;
    #pragma unroll
    for (int r = 0; r < 4; ++r) op[(long)r * HID] = acc[r];
  }
}

// ---------------------------------------------------------------------------
// Kernel 2 (v6): h_t = relu(xp_t + W_hh h_{t-1}).  One block per chain,
// 512 threads = 8 waves = 2 waves/SIMD (TLP to hide LDS/DPP/barrier latency).
// lane l of wave w: g = l&7 (32-col K-chunk), quad q = l>>3.
// Thread: 4 partial outputs (rows 32w+4q .. +4) over chunk g = 64 fdot2.
// Reduce-scatter with DPP masks {XOR7, XOR2, XOR1} (XOR4 not a DPP ctrl;
// 7^2^1=4 closes the chunk group):
//   A: XOR7, keep index bit1 == (l>>2)&1
//   B: XOR2, keep index bit0 == (l>>1)&1
//   C: XOR1, all-reduce (partner shares final index)
// -> lanes {l, l^1} BOTH own output j = 32w + 4*(l>>3) + ((l>>1)&3) (dup
// stores are benign: same value, same address).  Branch-free epilogue:
// fmax, 1 dword store, 1 ds_write_b16, 1 dword xp load (uniform clamped
// address, 4-deep pipeline) -> deterministic counted vmcnt; globals stay in
// flight across the lgkmcnt-only barrier.
// LDS h: chunk g at byte 80g -> each ds_read_b128 hits 8 disjoint bank
// quads (20g mod 32) -> conflict-free.
// ---------------------------------------------------------------------------
#define RNN_BAR() asm volatile("s_waitcnt lgkmcnt(0)\n\ts_barrier" ::: "memory")

#define RNN_STEP(U, XQ)                                                        \
  {                                                                            \
    const int t = t4 + (U);                                                    \
    /* prefetch xp for step t+4 (uniform clamped addr, always executes) */     \
    const int tp = (t + 4 < T) ? (t + 4) : (T - 1);                            \
    float xnew = outp[(long)tp * HID];                                         \
    half8_t hv[4];                                                             \
    _Pragma("unroll")                                                          \
    for (int s = 0; s < 4; ++s)                                                \
      hv[s] = *(const half8_t*)(hraw[(U) & 1] + rb + 16 * s);                  \
    float a0 = 0.f, a1 = 0.f, a2 = 0.f, a3 = 0.f;                              \
    _Pragma("unroll")                                                          \
    for (int s = 0; s < 4; ++s) {                                              \
      a0 = __builtin_amdgcn_fdot2(H2X(w8[0][s], 0), H2X(hv[s], 0), a0, false); \
      a0 = __builtin_amdgcn_fdot2(H2X(w8[0][s], 1), H2X(hv[s], 1), a0, false); \
      a0 = __builtin_amdgcn_fdot2(H2X(w8[0][s], 2), H2X(hv[s], 2), a0, false); \
      a0 = __builtin_amdgcn_fdot2(H2X(w8[0][s], 3), H2X(hv[s], 3), a0, false); \
      a1 = __builtin_amdgcn_fdot2(H2X(w8[1][s], 0), H2X(hv[s], 0), a1, false); \
      a1 = __builtin_amdgcn_fdot2(H2X(w8[1][s], 1), H2X(hv[s], 1), a1, false); \
      a1 = __builtin_amdgcn_fdot2(H2X(w8[1][s], 2), H2X(hv[s], 2), a1, false); \
      a1 = __builtin_amdgcn_fdot2(H2X(w8[1][s], 3), H2X(hv[s], 3), a1, false); \
      a2 = __builtin_amdgcn_fdot2(H2X(w8[2][s], 0), H2X(hv[s], 0), a2, false); \
      a2 = __builtin_amdgcn_fdot2(H2X(w8[2][s], 1), H2X(hv[s], 1), a2, false); \
      a2 = __builtin_amdgcn_fdot2(H2X(w8[2][s], 2), H2X(hv[s], 2), a2, false); \
      a2 = __builtin_amdgcn_fdot2(H2X(w8[2][s], 3), H2X(hv[s], 3), a2, false); \
      a3 = __builtin_amdgcn_fdot2(H2X(w8[3][s], 0), H2X(hv[s], 0), a3, false); \
      a3 = __builtin_amdgcn_fdot2(H2X(w8[3][s], 1), H2X(hv[s], 1), a3, false); \
      a3 = __builtin_amdgcn_fdot2(H2X(w8[3][s], 2), H2X(hv[s], 2), a3, false); \
      a3 = __builtin_amdgcn_fdot2(H2X(w8[3][s], 3), H2X(hv[s], 3), a3, false); \
    }                                                                          \
    /* reduce-scatter: lanes {l,l^1} end with full sum of index (l>>1)&3 */    \
    float r0 = kA ? a0 : a2;   /* stage A: XOR7, keep bit1==kA */              \
    float r1 = kA ? a1 : a3;                                                   \
    float b0 = (kA ? a2 : a0) + dpp_mov<0x141>(r0);                            \
    float b1 = (kA ? a3 : a1) + dpp_mov<0x141>(r1);                            \
    float rB = kB ? b0 : b1;   /* stage B: XOR2, keep bit0==kB */              \
    float c  = (kB ? b1 : b0) + dpp_mov<0x4E>(rB);                             \
    float fin = c + dpp_mov<0xB1>(c);   /* stage C: XOR1 all-reduce */         \
    float y = fmaxf(fin + (XQ), 0.f);                                          \
    outp[(long)t * HID] = y;                                                   \
    *(half_t*)(hraw[((U) & 1) ^ 1] + hwb) = (half_t)y;                         \
    XQ = xnew;                                                                 \
    RNN_BAR();                                                                 \
  }

__global__ __launch_bounds__(512, 1) void rnn_kernel(
    const float* __restrict__ Whh, float* __restrict__ out, int T)
{
  // 8 chunks x (64B data + 16B pad), double buffered
  __shared__ alignas(128) unsigned char hraw[2][8 * 80];

  const int tid = threadIdx.x;
  const int l   = tid & 63;
  const int w   = tid >> 6;                // wave 0..7
  const int g   = l & 7;                   // K-chunk: columns [32g, 32g+32)
  const int j0  = w * 32 + (l >> 3) * 4;   // partial rows [j0, j0+4)
  const int rb  = g * 80;                  // LDS read base (bytes)
  const int jown = j0 + ((l >> 1) & 3);    // output row OWNED post-reduce
  const int hwb = ((jown >> 5) * 80 + (jown & 31) * 2);  // LDS write byte
  const bool kA = (l & 4) != 0;
  const bool kB = (l & 2) != 0;
  float* outp = out + (long)blockIdx.x * SEQT * HID + jown;

  // W_hh[j0+i][32g + 8s .. +8] -> w8[i][s]  (64 VGPRs, static indexing)
  half8_t w8[4][4];
  #pragma unroll
  for (int i = 0; i < 4; ++i) {
    const float* wr = Whh + (long)(j0 + i) * HID + g * 32;
    #pragma unroll
    for (int s = 0; s < 4; ++s) {
      float4_t v0 = *(const float4_t*)(wr + s * 8);
      float4_t v1 = *(const float4_t*)(wr + s * 8 + 4);
      w8[i][s] = cvt8(v0, v1);
    }
  }

  // h_0 = 0 (covers data+pads of buffer 0)
  if (tid < 160) ((float*)hraw[0])[tid] = 0.f;

  // 4-deep xp prefetch (named registers -> static indexing), all lanes
  float xq0 = outp[0L * HID];
  float xq1 = outp[1L * HID];
  float xq2 = outp[2L * HID];
  float xq3 = outp[3L * HID];
  RNN_BAR();

  #pragma unroll 1
  for (int t4 = 0; t4 < T; t4 += 4) {
    RNN_STEP(0, xq0)
    RNN_STEP(1, xq1)
    RNN_STEP(2, xq2)
    RNN_STEP(3, xq3)
  }
}

extern "C" void kernel_launch(void* const* d_in, const int* in_sizes, int n_in,
                              void* d_out, int out_size, void* d_ws, size_t ws_size,
                              hipStream_t stream) {
  const float* x   = (const float*)d_in[0];
  const float* Wxh = (const float*)d_in[1];
  const float* Whh = (const float*)d_in[2];
  const float* bh  = (const float*)d_in[3];
  float* out = (float*)d_out;

  if (ws_size >= (size_t)(DIM * HID * sizeof(half_t))) {
    half_t* Wh = (half_t*)d_ws;
    cvt_w_kernel<<<dim3((DIM * HID) / 1024), dim3(256), 0, stream>>>(Wxh, Wh);
    xproj_f16_kernel<<<dim3((BATCH * SEQT) / 64), dim3(256), 0, stream>>>(x, Wh, bh, out);
  } else {
    xproj_kernel<<<dim3((BATCH * SEQT) / 64), dim3(256), 0, stream>>>(x, Wxh, bh, out);
  }
  rnn_kernel<<<dim3(BATCH), dim3(512), 0, stream>>>(Whh, out, SEQT);
}